// Round 8
// baseline (115.700 us; speedup 1.0000x reference)
//
#include <hip/hip_runtime.h>
#include <hip/hip_bf16.h>

// NeuralGraphOutput: out[b,o] = sum_a mask[b,a] * relu( sum_f x[b,a,f] * W[f,o] + bias[o] )
//   x[b,a,:] = concat(atoms[b,a,0:64], sum_d bonds[b,a,d,0:16])   (80 features)
//   mask[b,a] = any(edges[b,a,d] != -1)
// B=2048, A=256, D=8, FA=64, FB=16, FP=256
//
// R8: de-convoy the phase structure. Only bonds(d-sum)+mask are LDS-staged
// (17.4KB); atoms are loaded global->reg as A-fragments INSIDE the compute
// strip loop (lane reads its own atoms[row][lgrp*8..+7] slices — contiguous,
// no cross-thread exchange needed). The compute phase now issues ~1/3 of the
// block's memory traffic, so the CU memory pipe no longer idles in lockstep
// during compute windows (R4-R7 plateau diagnosis).
//  - bonds LDS rows: pitch 66 bf16 (33 dwords) -> <=4-way on the one a2
//    ds_read_b128 per strip; pad k=80..95 stored as zeros in-row.
//  - W pre-swizzled fragments (prep kernel), prologue-resident (R5 lesson).
//  - partials + tiny reduce kernel unchanged.

#define NB 2048
#define NA 256
#define ND 8
#define NFA 64
#define NFB 16
#define NF 80
#define NFP 256
#define AH 128             // atoms per block (half molecule)
#define BPITCH 66          // bonds-sum LDS row pitch in bf16 elems (132B)

#define PART_OFF    (64 * 1024)          // partials start at 64KB in ws

typedef __attribute__((ext_vector_type(8))) short short8;   // 8 bf16 = 4 VGPR
typedef __attribute__((ext_vector_type(4))) float f32x4;    // MFMA C/D

static __device__ __forceinline__ unsigned int pk2bf(float lo, float hi) {
    // packed RNE fp32->bf16 pair; compiler emits v_cvt_pk_bf16_f32
    __hip_bfloat162 h = __float22bfloat162_rn(float2{lo, hi});
    return *reinterpret_cast<unsigned int*>(&h);
}

static __device__ __forceinline__ unsigned short f2bf(float f) {
    unsigned int u = __float_as_uint(f);
    return (unsigned short)((u + 0x7FFFu + ((u >> 16) & 1u)) >> 16);
}

// ---------- prep: W[80][256] fp32 -> bf16 B-fragments [ntg][ks][lane] ----------
__global__ void ngf_prep_w(const float* __restrict__ W, short8* __restrict__ wfrag)
{
    const int gid  = blockIdx.x;        // 0..47 = ntg*3 + ks
    const int nt   = gid / 3;
    const int ks   = gid % 3;
    const int lane = threadIdx.x;       // 0..63
    const int c    = nt * 16 + (lane & 15);
    short8 v;
    #pragma unroll
    for (int j = 0; j < 8; ++j) {
        const int k = ks * 32 + (lane >> 4) * 8 + j;
        float w = (k < NF) ? W[k * NFP + c] : 0.0f;
        v[j] = (short)f2bf(w);
    }
    wfrag[gid * 64 + lane] = v;
}

// ---------- main: half molecule per block ----------
__launch_bounds__(256, 4)
__global__ void ngf_mfma_kernel(const float4* __restrict__ atoms4,
                                const float4* __restrict__ bonds4,
                                const int4*   __restrict__ edges4,
                                const short8* __restrict__ wfrag,
                                const float*  __restrict__ bias,
                                float* __restrict__ part)
{
    const int bid  = blockIdx.x;         // 0..4095
    const int tid  = threadIdx.x;        // 0..255
    const int wave = tid >> 6;           // 0..3
    const int lane = tid & 63;
    const int lrow = lane & 15;          // A row / B col / C-D col
    const int lgrp = lane >> 4;          // k-group (A/B) / row-group (C/D)

    __shared__ unsigned short BS[AH * BPITCH];  // bonds-sum + zero pad, 16.9KB
    __shared__ float maskf[AH];                 // 512 B

    const size_t atomBase = (size_t)bid * AH;   // == mol*256 + half*128

    // ---------- W fragments: prologue, coalesced 16B loads (L2-hot) ----------
    short8 bf[3][4];
    float  bia[4];
    #pragma unroll
    for (int nt = 0; nt < 4; ++nt) {
        const int ntg = wave * 4 + nt;
        bia[nt] = bias[ntg * 16 + lrow];
        #pragma unroll
        for (int ks = 0; ks < 3; ++ks)
            bf[ks][nt] = wfrag[(ntg * 3 + ks) * 64 + lane];
    }

    // ---------- stage bonds d-sum + mask into LDS ----------
    // bonds: 4 threads per atom (q = quarter of the 16-fb row), 2 passes
    #pragma unroll
    for (int p = 0; p < 2; ++p) {
        const int a = p * 64 + (tid >> 2);
        const int q = tid & 3;
        const float4* bp = bonds4 + (atomBase + a) * 32 + q;   // atom row = 32 float4
        float4 s = {0.0f, 0.0f, 0.0f, 0.0f};
        #pragma unroll
        for (int d = 0; d < 8; ++d) {
            float4 v = bp[d * 4];
            s.x += v.x; s.y += v.y; s.z += v.z; s.w += v.w;
        }
        uint2 o;
        o.x = pk2bf(s.x, s.y);
        o.y = pk2bf(s.z, s.w);
        *(uint2*)&BS[a * BPITCH + q * 4] = o;          // fb data: elems 0..15
        uint2 z = {0u, 0u};
        *(uint2*)&BS[a * BPITCH + 16 + q * 4] = z;     // k=80..95 pad: elems 16..31
    }
    // edges -> mask
    if (tid < AH) {
        const int a = tid;
        int4 e0 = edges4[(atomBase + a) * 2];
        int4 e1 = edges4[(atomBase + a) * 2 + 1];
        bool any = (e0.x != -1) | (e0.y != -1) | (e0.z != -1) | (e0.w != -1)
                 | (e1.x != -1) | (e1.y != -1) | (e1.z != -1) | (e1.w != -1);
        maskf[a] = any ? 1.0f : 0.0f;
    }
    __syncthreads();

    // ---------- compute: 8 strips; atoms A-frags loaded DIRECT from global ----------
    float colsum[4] = {0.0f, 0.0f, 0.0f, 0.0f};
    #pragma unroll 2
    for (int s = 0; s < 8; ++s) {
        const int row = s * 16 + lrow;
        // atoms[row][lgrp*8 .. +7] (k-slice 0) and [32+lgrp*8 .. +7] (k-slice 1)
        const float4* ap = atoms4 + (atomBase + row) * 16 + lgrp * 2;
        float4 v0 = ap[0], v1 = ap[1];     // k = lgrp*8 + 0..7
        float4 v2 = ap[8], v3 = ap[9];     // k = 32 + lgrp*8 + 0..7
        union { short8 s8; uint4 u4; } ca, cb;
        ca.u4 = uint4{pk2bf(v0.x, v0.y), pk2bf(v0.z, v0.w),
                      pk2bf(v1.x, v1.y), pk2bf(v1.z, v1.w)};
        cb.u4 = uint4{pk2bf(v2.x, v2.y), pk2bf(v2.z, v2.w),
                      pk2bf(v3.x, v3.y), pk2bf(v3.z, v3.w)};
        short8 a0 = ca.s8;
        short8 a1 = cb.s8;
        // bonds-sum fragment (k 64..95; lgrp>=2 reads the zero pad)
        short8 a2 = *(const short8*)&BS[row * BPITCH + lgrp * 8];
        float4 m4 = *(const float4*)&maskf[s * 16 + lgrp * 4];
        #pragma unroll
        for (int nt = 0; nt < 4; ++nt) {
            f32x4 acc = {0.0f, 0.0f, 0.0f, 0.0f};
            acc = __builtin_amdgcn_mfma_f32_16x16x32_bf16(a0, bf[0][nt], acc, 0, 0, 0);
            acc = __builtin_amdgcn_mfma_f32_16x16x32_bf16(a1, bf[1][nt], acc, 0, 0, 0);
            acc = __builtin_amdgcn_mfma_f32_16x16x32_bf16(a2, bf[2][nt], acc, 0, 0, 0);
            const float bv = bia[nt];
            colsum[nt] += fmaxf(acc[0] + bv, 0.0f) * m4.x
                        + fmaxf(acc[1] + bv, 0.0f) * m4.y
                        + fmaxf(acc[2] + bv, 0.0f) * m4.z
                        + fmaxf(acc[3] + bv, 0.0f) * m4.w;
        }
    }

    // ---------- reduce row-groups, store partial ----------
    #pragma unroll
    for (int nt = 0; nt < 4; ++nt) {
        float v = colsum[nt];
        v += __shfl_xor(v, 16, 64);
        v += __shfl_xor(v, 32, 64);
        if (lane < 16)
            part[(size_t)bid * NFP + (wave * 4 + nt) * 16 + lane] = v;
    }
}

// ---------- reduce: out[mol][col] = part[2*mol][col] + part[2*mol+1][col] ----------
__global__ void ngf_reduce(const float* __restrict__ part, float* __restrict__ out)
{
    const int g   = blockIdx.x * 256 + threadIdx.x;   // 0..524287
    const int mol = g >> 8;
    const int col = g & 255;
    out[g] = part[(size_t)(2 * mol) * NFP + col] + part[(size_t)(2 * mol + 1) * NFP + col];
}

extern "C" void kernel_launch(void* const* d_in, const int* in_sizes, int n_in,
                              void* d_out, int out_size, void* d_ws, size_t ws_size,
                              hipStream_t stream) {
    const float4* atoms4 = (const float4*)d_in[0];
    const float4* bonds4 = (const float4*)d_in[1];
    const int4*   edges4 = (const int4*)d_in[2];
    const float*  W      = (const float*)d_in[3];
    const float*  bias   = (const float*)d_in[4];
    float* out = (float*)d_out;

    short8* wfrag = (short8*)d_ws;
    float*  part  = (float*)((char*)d_ws + PART_OFF);   // 4096*256 fp32 = 4 MB

    ngf_prep_w<<<48, 64, 0, stream>>>(W, wfrag);
    ngf_mfma_kernel<<<NB * 2, 256, 0, stream>>>(atoms4, bonds4, edges4, wfrag, bias, part);
    ngf_reduce<<<2048, 256, 0, stream>>>(part, out);
}

// Round 9
// 88.483 us; speedup vs baseline: 1.3076x; 1.3076x over previous
//
#include <hip/hip_runtime.h>
#include <hip/hip_bf16.h>

// NeuralGraphOutput: out[b,o] = sum_a mask[b,a] * relu( sum_f x[b,a,f] * W[f,o] + bias[o] )
//   x[b,a,:] = concat(atoms[b,a,0:64], sum_d bonds[b,a,d,0:16])   (80 features)
//   mask[b,a] = any(edges[b,a,d] != -1)
// B=2048, A=256, D=8, FA=64, FB=16, FP=256
//
// R9 = R6 structure (best: 89.5us) + latency-depth staging:
//  - ALL 26 staging loads per thread burst-issued into register arrays before
//    any processing (16 bonds float4 + 8 atoms float4 + 2 edges int4) ->
//    ~24KB in flight per CU instead of ~6KB (latency-limited diagnosis of the
//    89.5us plateau: need BW x latency = ~20KB in flight per CU).
//  - W-fragment loads moved AFTER staging (once per block, L2-hit overlaps the
//    barrier wait) so their 48 VGPRs are free to hold in-flight load data
//    during staging. NOT R5's per-nt reload (that thrashed L2 4x per block).
//  - everything else identical to R6: half-molecule blocks, PITCH=100 LDS,
//    prologue... er, pre-barrier wfrag, partials + tiny reduce.

#define NB 2048
#define NA 256
#define ND 8
#define NFA 64
#define NFB 16
#define NF 80
#define NFP 256
#define PITCH 100          // bf16 elems per LDS row (200B stride: conflict-free b128)
#define AH 128             // atoms per block (half molecule)

#define PART_OFF    (64 * 1024)          // partials start at 64KB in ws

typedef __attribute__((ext_vector_type(8))) short short8;   // 8 bf16 = 4 VGPR
typedef __attribute__((ext_vector_type(4))) float f32x4;    // MFMA C/D

static __device__ __forceinline__ unsigned int pk2bf(float lo, float hi) {
    // packed RNE fp32->bf16 pair; compiler emits v_cvt_pk_bf16_f32
    __hip_bfloat162 h = __float22bfloat162_rn(float2{lo, hi});
    return *reinterpret_cast<unsigned int*>(&h);
}

static __device__ __forceinline__ unsigned short f2bf(float f) {
    unsigned int u = __float_as_uint(f);
    return (unsigned short)((u + 0x7FFFu + ((u >> 16) & 1u)) >> 16);
}

// ---------- prep: W[80][256] fp32 -> bf16 B-fragments [ntg][ks][lane] ----------
__global__ void ngf_prep_w(const float* __restrict__ W, short8* __restrict__ wfrag)
{
    const int gid  = blockIdx.x;        // 0..47 = ntg*3 + ks
    const int nt   = gid / 3;
    const int ks   = gid % 3;
    const int lane = threadIdx.x;       // 0..63
    const int c    = nt * 16 + (lane & 15);
    short8 v;
    #pragma unroll
    for (int j = 0; j < 8; ++j) {
        const int k = ks * 32 + (lane >> 4) * 8 + j;
        float w = (k < NF) ? W[k * NFP + c] : 0.0f;
        v[j] = (short)f2bf(w);
    }
    wfrag[gid * 64 + lane] = v;
}

// ---------- main: half molecule per block ----------
__launch_bounds__(256, 4)
__global__ void ngf_mfma_kernel(const float4* __restrict__ atoms4,
                                const float4* __restrict__ bonds4,
                                const int4*   __restrict__ edges4,
                                const short8* __restrict__ wfrag,
                                const float*  __restrict__ bias,
                                float* __restrict__ part)
{
    const int bid  = blockIdx.x;         // 0..4095
    const int tid  = threadIdx.x;        // 0..255
    const int wave = tid >> 6;           // 0..3
    const int lane = tid & 63;
    const int lrow = lane & 15;          // A row / B col / C-D col
    const int lgrp = lane >> 4;          // k-group (A/B) / row-group (C/D)

    __shared__ unsigned short X[AH * PITCH];   // 25600 B
    __shared__ float maskf[AH];                // 512 B

    const size_t atomBase = (size_t)bid * AH;  // == mol*256 + half*128

    // ================= staging: burst-issue ALL loads first =================
    const int ba = tid >> 2;            // bonds atom (pass0); pass1 = +64
    const int q  = tid & 3;             // quarter of the 16-fb row
    const float4* bp0 = bonds4 + (atomBase + ba) * 32 + q;        // row = 32 float4
    const float4* bp1 = bonds4 + (atomBase + 64 + ba) * 32 + q;

    float4 bv[16];
    #pragma unroll
    for (int d = 0; d < 8; ++d) bv[d] = bp0[d * 4];
    #pragma unroll
    for (int d = 0; d < 8; ++d) bv[8 + d] = bp1[d * 4];

    float4 av[8];
    #pragma unroll
    for (int it = 0; it < 8; ++it) {
        const int flat = it * 256 + tid;
        av[it] = atoms4[(atomBase + (flat >> 4)) * 16 + (flat & 15)];
    }

    // edges: all threads load (tid>=128 duplicates hit L1), store under mask
    const int ea = tid & 127;
    int4 e0 = edges4[(atomBase + ea) * 2];
    int4 e1 = edges4[(atomBase + ea) * 2 + 1];

    // ---------------- process (vmcnt-ordered: bonds complete first) ----------
    {   // bonds pass 0
        float4 s = {0.0f, 0.0f, 0.0f, 0.0f};
        #pragma unroll
        for (int d = 0; d < 8; ++d) { s.x += bv[d].x; s.y += bv[d].y; s.z += bv[d].z; s.w += bv[d].w; }
        uint2 o; o.x = pk2bf(s.x, s.y); o.y = pk2bf(s.z, s.w);
        *(uint2*)&X[ba * PITCH + NFA + q * 4] = o;
    }
    {   // bonds pass 1
        float4 s = {0.0f, 0.0f, 0.0f, 0.0f};
        #pragma unroll
        for (int d = 0; d < 8; ++d) { s.x += bv[8 + d].x; s.y += bv[8 + d].y; s.z += bv[8 + d].z; s.w += bv[8 + d].w; }
        uint2 o; o.x = pk2bf(s.x, s.y); o.y = pk2bf(s.z, s.w);
        *(uint2*)&X[(64 + ba) * PITCH + NFA + q * 4] = o;
    }
    // atoms
    #pragma unroll
    for (int it = 0; it < 8; ++it) {
        const int flat = it * 256 + tid;
        const int a = flat >> 4, k4 = flat & 15;
        uint2 o; o.x = pk2bf(av[it].x, av[it].y); o.y = pk2bf(av[it].z, av[it].w);
        *(uint2*)&X[a * PITCH + k4 * 4] = o;
    }
    // mask + K pad (k=80..95)
    if (tid < AH) {
        bool any = (e0.x != -1) | (e0.y != -1) | (e0.z != -1) | (e0.w != -1)
                 | (e1.x != -1) | (e1.y != -1) | (e1.z != -1) | (e1.w != -1);
        maskf[ea] = any ? 1.0f : 0.0f;
        uint4 z = {0u, 0u, 0u, 0u};
        *(uint4*)&X[ea * PITCH + 80] = z;
        *(uint4*)&X[ea * PITCH + 88] = z;
    }

    // ---------- W fragments: once per block, overlaps barrier wait ----------
    short8 bf[3][4];
    float  bia[4];
    #pragma unroll
    for (int nt = 0; nt < 4; ++nt) {
        const int ntg = wave * 4 + nt;
        bia[nt] = bias[ntg * 16 + lrow];
        #pragma unroll
        for (int ks = 0; ks < 3; ++ks)
            bf[ks][nt] = wfrag[(ntg * 3 + ks) * 64 + lane];
    }
    __syncthreads();

    // ---------- compute: 8 strips of 16 atoms; wave owns 64 output cols ----------
    float colsum[4] = {0.0f, 0.0f, 0.0f, 0.0f};
    #pragma unroll 2
    for (int s = 0; s < 8; ++s) {
        const int row = s * 16 + lrow;
        const unsigned short* xr = &X[row * PITCH + lgrp * 8];
        short8 a0 = *(const short8*)(xr);          // k  0..31
        short8 a1 = *(const short8*)(xr + 32);     // k 32..63
        short8 a2 = *(const short8*)(xr + 64);     // k 64..95 (pad zeros)
        float4 m4 = *(const float4*)&maskf[s * 16 + lgrp * 4];
        #pragma unroll
        for (int nt = 0; nt < 4; ++nt) {
            f32x4 acc = {0.0f, 0.0f, 0.0f, 0.0f};
            acc = __builtin_amdgcn_mfma_f32_16x16x32_bf16(a0, bf[0][nt], acc, 0, 0, 0);
            acc = __builtin_amdgcn_mfma_f32_16x16x32_bf16(a1, bf[1][nt], acc, 0, 0, 0);
            acc = __builtin_amdgcn_mfma_f32_16x16x32_bf16(a2, bf[2][nt], acc, 0, 0, 0);
            const float bv2 = bia[nt];
            colsum[nt] += fmaxf(acc[0] + bv2, 0.0f) * m4.x
                        + fmaxf(acc[1] + bv2, 0.0f) * m4.y
                        + fmaxf(acc[2] + bv2, 0.0f) * m4.z
                        + fmaxf(acc[3] + bv2, 0.0f) * m4.w;
        }
    }

    // ---------- reduce row-groups, store partial ----------
    #pragma unroll
    for (int nt = 0; nt < 4; ++nt) {
        float v = colsum[nt];
        v += __shfl_xor(v, 16, 64);
        v += __shfl_xor(v, 32, 64);
        if (lane < 16)
            part[(size_t)bid * NFP + (wave * 4 + nt) * 16 + lane] = v;
    }
}

// ---------- reduce: out[mol][col] = part[2*mol][col] + part[2*mol+1][col] ----------
__global__ void ngf_reduce(const float* __restrict__ part, float* __restrict__ out)
{
    const int g   = blockIdx.x * 256 + threadIdx.x;   // 0..524287
    const int mol = g >> 8;
    const int col = g & 255;
    out[g] = part[(size_t)(2 * mol) * NFP + col] + part[(size_t)(2 * mol + 1) * NFP + col];
}

extern "C" void kernel_launch(void* const* d_in, const int* in_sizes, int n_in,
                              void* d_out, int out_size, void* d_ws, size_t ws_size,
                              hipStream_t stream) {
    const float4* atoms4 = (const float4*)d_in[0];
    const float4* bonds4 = (const float4*)d_in[1];
    const int4*   edges4 = (const int4*)d_in[2];
    const float*  W      = (const float*)d_in[3];
    const float*  bias   = (const float*)d_in[4];
    float* out = (float*)d_out;

    short8* wfrag = (short8*)d_ws;
    float*  part  = (float*)((char*)d_ws + PART_OFF);   // 4096*256 fp32 = 4 MB

    ngf_prep_w<<<48, 64, 0, stream>>>(W, wfrag);
    ngf_mfma_kernel<<<NB * 2, 256, 0, stream>>>(atoms4, bonds4, edges4, wfrag, bias, part);
    ngf_reduce<<<2048, 256, 0, stream>>>(part, out);
}